// Round 1
// baseline (486.864 us; speedup 1.0000x reference)
//
#include <hip/hip_runtime.h>
#include <math.h>

#define N_PTS 300000
#define NJ 80          // K joints
#define FDIM 64        // feature dim
#define VN 6890        // smpl verts
#define TILE 256
#define NTILES ((N_PTS + TILE - 1) / TILE)   // 1172

// ---------------------------------------------------------------------------
// kA: fused  a = softmax(-sqdist(feature, centers))  and
//            jacc[k][c] += sum_n a[n][k] * data[n][c]
//     data cols: 0..63 = feature, 64..66 = xyz, 67 = 1 (cnt)
// ---------------------------------------------------------------------------
__global__ __launch_bounds__(256) void kA(
    const float* __restrict__ xyz, const float* __restrict__ feature,
    const float* __restrict__ centers, float* __restrict__ jacc)
{
  __shared__ float s_cn[NJ];          // |c_k|^2
  __shared__ float s_at[64][NJ];      // a subtile: 64 points x 80 joints

  const int tid  = threadIdx.x;
  const int wid  = tid >> 6;
  const int lane = tid & 63;

  if (tid < NJ) {
    float s = 0.f;
    const float* c = centers + tid * FDIM;
    for (int j = 0; j < FDIM; ++j) s += c[j] * c[j];
    s_cn[tid] = s;
  }
  __syncthreads();

  // phase-2 output mapping: primary = feature cols
  const int pc  = tid & 63;            // col 0..63
  const int pk0 = 20 * (tid >> 6);     // k0 in {0,20,40,60}
  float accP[20];
  #pragma unroll
  for (int i = 0; i < 20; ++i) accP[i] = 0.f;
  // extra cols (xyz + cnt)
  const int ek0 = tid >> 2;            // k 0..63
  const int ec  = tid & 3;             // col 64+ec (ec==3 -> ones)
  float accE0 = 0.f, accE1 = 0.f;      // accE1 (tid<64): k = 64+ek0

  for (int tile = blockIdx.x; tile < NTILES; tile += gridDim.x) {
    const int base = tile * TILE;
    const int n = base + tid;
    float a[NJ];

    if (n < N_PTS) {
      #pragma unroll
      for (int k = 0; k < NJ; ++k) a[k] = 0.f;
      const float4* frow = (const float4*)(feature + (size_t)n * FDIM);
      const float4* c4 = (const float4*)centers;
      for (int j = 0; j < FDIM / 4; ++j) {
        float4 f = frow[j];
        #pragma unroll
        for (int k = 0; k < NJ; ++k) {
          float4 c = c4[k * (FDIM / 4) + j];   // uniform -> s_load
          a[k] += f.x * c.x + f.y * c.y + f.z * c.z + f.w * c.w;
        }
      }
      float m = -1e30f;
      #pragma unroll
      for (int k = 0; k < NJ; ++k) {
        a[k] = 2.f * a[k] - s_cn[k];
        m = fmaxf(m, a[k]);
      }
      float s = 0.f;
      #pragma unroll
      for (int k = 0; k < NJ; ++k) { a[k] = __expf(a[k] - m); s += a[k]; }
      float rs = 1.f / s;
      #pragma unroll
      for (int k = 0; k < NJ; ++k) a[k] *= rs;
    } else {
      #pragma unroll
      for (int k = 0; k < NJ; ++k) a[k] = 0.f;
    }

    // 4 subtiles of 64 points
    for (int s4 = 0; s4 < 4; ++s4) {
      if (wid == s4) {
        #pragma unroll
        for (int j = 0; j < NJ / 4; ++j)
          *(float4*)&s_at[lane][4 * j] =
              make_float4(a[4*j], a[4*j+1], a[4*j+2], a[4*j+3]);
      }
      __syncthreads();
      const int sb = base + s4 * 64;

      for (int nn = 0; nn < 64; ++nn) {
        const int gn = sb + nn;
        float d = (gn < N_PTS) ? feature[(size_t)gn * FDIM + pc] : 0.f;
        #pragma unroll
        for (int i5 = 0; i5 < 5; ++i5) {
          float4 av = *(const float4*)&s_at[nn][pk0 + 4 * i5];
          accP[4*i5+0] += av.x * d;
          accP[4*i5+1] += av.y * d;
          accP[4*i5+2] += av.z * d;
          accP[4*i5+3] += av.w * d;
        }
      }
      // xyz / cnt columns
      for (int nn = 0; nn < 64; ++nn) {
        const int gn = sb + nn;
        float d = 0.f;
        if (gn < N_PTS) d = (ec == 3) ? 1.f : xyz[(size_t)gn * 3 + ec];
        accE0 += s_at[nn][ek0] * d;
        if (tid < 64) accE1 += s_at[nn][64 + ek0] * d;
      }
      __syncthreads();
    }
  }

  #pragma unroll
  for (int i5 = 0; i5 < 5; ++i5)
    #pragma unroll
    for (int j = 0; j < 4; ++j)
      atomicAdd(&jacc[(pk0 + 4*i5 + j) * 68 + pc], accP[4*i5+j]);
  atomicAdd(&jacc[ek0 * 68 + 64 + ec], accE0);
  if (tid < 64) atomicAdd(&jacc[(64 + ek0) * 68 + 64 + ec], accE1);
}

// ---------------------------------------------------------------------------
// kB0: finalize joints (divide by cnt), |j|^2, lo/hi over smpl verts
// ---------------------------------------------------------------------------
__global__ __launch_bounds__(256) void kB0(
    const float* __restrict__ jacc, const float* __restrict__ smpl,
    float* __restrict__ jfeat, float* __restrict__ jpack,
    float* __restrict__ lohi)
{
  const int tid = threadIdx.x;
  for (int i = tid; i < NJ * 68; i += 256) {
    int k = i / 68, c = i % 68;
    if (c == 67) continue;
    float cnt = jacc[k * 68 + 67] + 1e-6f;
    float v = jacc[i] / cnt;
    if (c < 64) jfeat[k * 64 + c] = v;
    else        jpack[k * 4 + (c - 64)] = v;
  }
  __syncthreads();
  if (tid < NJ) {
    float x = jpack[tid*4], y = jpack[tid*4+1], z = jpack[tid*4+2];
    jpack[tid*4+3] = x*x + y*y + z*z;
  }
  float lo[3] = {1e30f,1e30f,1e30f}, hi[3] = {-1e30f,-1e30f,-1e30f};
  for (int v = tid; v < VN; v += 256)
    for (int c = 0; c < 3; ++c) {
      float t = smpl[v*3+c];
      lo[c] = fminf(lo[c], t); hi[c] = fmaxf(hi[c], t);
    }
  __shared__ float red[256][6];
  for (int c = 0; c < 3; ++c) { red[tid][c] = lo[c]; red[tid][3+c] = hi[c]; }
  __syncthreads();
  for (int off = 128; off > 0; off >>= 1) {
    if (tid < off)
      for (int c = 0; c < 3; ++c) {
        red[tid][c]   = fminf(red[tid][c],   red[tid+off][c]);
        red[tid][3+c] = fmaxf(red[tid][3+c], red[tid+off][3+c]);
      }
    __syncthreads();
  }
  if (tid < 6) lohi[tid] = red[0][tid];
}

// ---------------------------------------------------------------------------
// kB1: per-joint argmin over smpl verts (one block per joint)
// ---------------------------------------------------------------------------
__global__ __launch_bounds__(256) void kB1(
    const float* __restrict__ jpack, const float* __restrict__ smpl,
    int* __restrict__ idxbuf)
{
  const int k = blockIdx.x;
  const int tid = threadIdx.x;
  const float jx = jpack[k*4], jy = jpack[k*4+1], jz = jpack[k*4+2];
  float best = 1e30f; int bi = 0;
  for (int v = tid; v < VN; v += 256) {
    float dx = smpl[v*3]   - jx;
    float dy = smpl[v*3+1] - jy;
    float dz = smpl[v*3+2] - jz;
    float d = dx*dx + dy*dy + dz*dz;
    if (d < best) { best = d; bi = v; }
  }
  __shared__ float sd[256]; __shared__ int si[256];
  sd[tid] = best; si[tid] = bi;
  __syncthreads();
  for (int off = 128; off > 0; off >>= 1) {
    if (tid < off) {
      float d2 = sd[tid+off]; int i2 = si[tid+off];
      if (d2 < sd[tid] || (d2 == sd[tid] && i2 < si[tid])) {
        sd[tid] = d2; si[tid] = i2;
      }
    }
    __syncthreads();
  }
  if (tid == 0) idxbuf[k] = si[0];
}

// ---------------------------------------------------------------------------
// kB2: full joint MLP chain -> qpack[80][4] (normalized), tpack[80][4]
// ---------------------------------------------------------------------------
__global__ __launch_bounds__(512) void kB2(
    const float* __restrict__ jfeat, const float* __restrict__ jpack,
    const float* __restrict__ lohi, const int* __restrict__ idxbuf,
    const float* __restrict__ sw, const float* __restrict__ bpf,
    const float* __restrict__ w_body, const float* __restrict__ b_body,
    const float* __restrict__ w_pos1, const float* __restrict__ b_pos1,
    const float* __restrict__ w_pos2, const float* __restrict__ b_pos2,
    const float* __restrict__ w_rot,  const float* __restrict__ b_rot,
    const float* __restrict__ w_trans,const float* __restrict__ b_trans,
    float* __restrict__ qpack, float* __restrict__ tpack)
{
  __shared__ float bufA[NJ][128];
  __shared__ float bufB[NJ][68];
  const int tid = threadIdx.x;

  // layer 0: g_in = [body_feat | joint_feat]
  for (int o = tid; o < NJ * 128; o += 512) {
    int k = o >> 7, c = o & 127;
    float v;
    if (c < 64) {
      int vid = idxbuf[k];
      float s = 0.f;
      for (int j = 0; j < 24; ++j) s += sw[vid * 24 + j] * bpf[j * 64 + c];
      v = s;
    } else {
      v = jfeat[k * 64 + (c - 64)];
    }
    bufA[k][c] = v;
  }
  __syncthreads();

  // layer 1: g = gelu(g_in @ w_body + b_body) -> bufB[3..66]; xn -> bufB[0..2]
  for (int o = tid; o < NJ * 64; o += 512) {
    int k = o >> 6, m = o & 63;
    float s = b_body[m];
    for (int i = 0; i < 128; ++i) s += bufA[k][i] * w_body[i * 64 + m];
    float u = 0.7978845608028654f * (s + 0.044715f * s * s * s);
    float e = __expf(2.f * u);
    float th = 1.f - 2.f / (e + 1.f);
    bufB[k][3 + m] = 0.5f * s * (1.f + th);
  }
  if (tid < NJ * 3) {
    int k = tid / 3, c = tid % 3;
    float lo = lohi[c], hi = lohi[3 + c];
    bufB[k][c] = 2.f * (jpack[k * 4 + c] - lo) / (hi - lo + 1e-6f) - 1.f;
  }
  __syncthreads();

  // layer 2: h = relu([xn|g] @ w_pos1 + b_pos1) -> bufA[80][128]
  for (int o = tid; o < NJ * 128; o += 512) {
    int k = o >> 7, m = o & 127;
    float s = b_pos1[m];
    for (int i = 0; i < 67; ++i) s += bufB[k][i] * w_pos1[i * 128 + m];
    bufA[k][m] = fmaxf(s, 0.f);
  }
  __syncthreads();

  // layer 3: g2 = h @ w_pos2 + b_pos2 -> bufB[0..63]
  for (int o = tid; o < NJ * 64; o += 512) {
    int k = o >> 6, m = o & 63;
    float s = b_pos2[m];
    for (int i = 0; i < 128; ++i) s += bufA[k][i] * w_pos2[i * 64 + m];
    bufB[k][m] = s;
  }
  __syncthreads();

  // layer 4: q (normalized) and t
  if (tid < NJ) {
    int k = tid;
    float q[4];
    for (int j = 0; j < 4; ++j) {
      float s = b_rot[j];
      for (int i = 0; i < 64; ++i) s += bufB[k][i] * w_rot[i * 4 + j];
      q[j] = s;
    }
    float nrm = sqrtf(q[0]*q[0]+q[1]*q[1]+q[2]*q[2]+q[3]*q[3]) + 1e-6f;
    float rn = 1.f / nrm;
    for (int j = 0; j < 4; ++j) qpack[k * 4 + j] = q[j] * rn;
    for (int j = 0; j < 3; ++j) {
      float s = b_trans[j];
      for (int i = 0; i < 64; ++i) s += bufB[k][i] * w_trans[i * 3 + j];
      tpack[k * 4 + j] = s;
    }
    tpack[k * 4 + 3] = 0.f;
  }
}

// ---------------------------------------------------------------------------
// kC: per-point joint softmax + quaternion blend
// ---------------------------------------------------------------------------
__global__ __launch_bounds__(256) void kC(
    const float* __restrict__ xyz, const float* __restrict__ jpack,
    const float* __restrict__ qpack, const float* __restrict__ tpack,
    float* __restrict__ out)
{
  const int stride = gridDim.x * 256;
  for (int p = blockIdx.x * 256 + threadIdx.x; p < N_PTS; p += stride) {
    float x0 = xyz[p*3], x1 = xyz[p*3+1], x2 = xyz[p*3+2];
    float l[NJ];
    float m = -1e30f;
    #pragma unroll
    for (int k = 0; k < NJ; ++k) {
      float4 j = *(const float4*)(jpack + k*4);
      l[k] = (2.f*(x0*j.x + x1*j.y + x2*j.z) - j.w) * 10.0f;  // 1/SIGMA
      m = fmaxf(m, l[k]);
    }
    float s = 0.f;
    float qb0=0,qb1=0,qb2=0,qb3=0, tb0=0,tb1=0,tb2=0;
    #pragma unroll
    for (int k = 0; k < NJ; ++k) {
      float e = __expf(l[k] - m);
      s += e;
      float4 q = *(const float4*)(qpack + k*4);
      float4 t = *(const float4*)(tpack + k*4);
      qb0 += e*q.x; qb1 += e*q.y; qb2 += e*q.z; qb3 += e*q.w;
      tb0 += e*t.x; tb1 += e*t.y; tb2 += e*t.z;
    }
    float rs = 1.f / s;
    qb0*=rs; qb1*=rs; qb2*=rs; qb3*=rs; tb0*=rs; tb1*=rs; tb2*=rs;
    float nrm = sqrtf(qb0*qb0+qb1*qb1+qb2*qb2+qb3*qb3) + 1e-6f;
    float rn = 1.f / nrm;
    float qw = qb0*rn, qx = qb1*rn, qy = qb2*rn, qz = qb3*rn;
    float t2x = 2.f*(qy*x2 - qz*x1);
    float t2y = 2.f*(qz*x0 - qx*x2);
    float t2z = 2.f*(qx*x1 - qy*x0);
    float cx = qy*t2z - qz*t2y;
    float cy = qz*t2x - qx*t2z;
    float cz = qx*t2y - qy*t2x;
    out[p*3]   = x0 + qw*t2x + cx + tb0;
    out[p*3+1] = x1 + qw*t2y + cy + tb1;
    out[p*3+2] = x2 + qw*t2z + cz + tb2;
  }
}

// ---------------------------------------------------------------------------
extern "C" void kernel_launch(void* const* d_in, const int* in_sizes, int n_in,
                              void* d_out, int out_size, void* d_ws, size_t ws_size,
                              hipStream_t stream) {
  const float* xyz     = (const float*)d_in[0];
  const float* feature = (const float*)d_in[1];
  const float* centers = (const float*)d_in[2];
  const float* smpl    = (const float*)d_in[3];
  const float* sw      = (const float*)d_in[4];
  const float* bpf     = (const float*)d_in[5];
  const float* w_body  = (const float*)d_in[6];
  const float* b_body  = (const float*)d_in[7];
  const float* w_pos1  = (const float*)d_in[8];
  const float* b_pos1  = (const float*)d_in[9];
  const float* w_pos2  = (const float*)d_in[10];
  const float* b_pos2  = (const float*)d_in[11];
  const float* w_rot   = (const float*)d_in[12];
  const float* b_rot   = (const float*)d_in[13];
  const float* w_trans = (const float*)d_in[14];
  const float* b_trans = (const float*)d_in[15];
  float* out = (float*)d_out;

  float* ws    = (float*)d_ws;
  float* jacc  = ws;              // 80*68 = 5440
  float* jfeat = ws + 5440;       // 80*64 = 5120
  float* jpack = ws + 10560;      // 80*4
  float* qpack = ws + 10880;      // 80*4
  float* tpack = ws + 11200;      // 80*4
  float* lohi  = ws + 11520;      // 6 (+2 pad)
  int*   idxbuf = (int*)(ws + 11528); // 80

  hipMemsetAsync(jacc, 0, 5440 * sizeof(float), stream);
  kA<<<dim3(1024), dim3(256), 0, stream>>>(xyz, feature, centers, jacc);
  kB0<<<dim3(1), dim3(256), 0, stream>>>(jacc, smpl, jfeat, jpack, lohi);
  kB1<<<dim3(NJ), dim3(256), 0, stream>>>(jpack, smpl, idxbuf);
  kB2<<<dim3(1), dim3(512), 0, stream>>>(jfeat, jpack, lohi, idxbuf, sw, bpf,
                                         w_body, b_body, w_pos1, b_pos1,
                                         w_pos2, b_pos2, w_rot, b_rot,
                                         w_trans, b_trans, qpack, tpack);
  kC<<<dim3(1024), dim3(256), 0, stream>>>(xyz, jpack, qpack, tpack, out);
}